// Round 10
// baseline (226.917 us; speedup 1.0000x reference)
//
#include <hip/hip_runtime.h>
#include <hip/hip_bf16.h>

// NRI edge-MLP encoder, fused single kernel (NO workspace):
// out[b,e,:] = relu(concat(x[b,send(e)], x[b,recv(e)]) @ W1^T + b1) @ W2^T + b2
// B=8, N=256, E=65280, n_in=64, n_hid=128, n_out=64.
// edge e: recv = e/255, k = e%255, send = k + (k >= recv)
//
// Round-10: phase-stagger. R9 kernel ~43us ~= SERIAL sum of LDS read time
// (940MB @ 69TB/s = 13.6us) + HBM write stream (134MB @ 6.7TB/s = 20us) +
// staging/issue (~6us): all waves leave the staging barrier together and run
// the same program, so the whole CU alternates LDS-convoy / store-convoy
// phases instead of mixing them. Fix: each wave walks its 4 independent
// edge-groups in rotated order g = (gi + wave) & 3. Half the waves sit in
// phase-1 (LDS) while half sit in phase-2/stores (VMEM) -> pipes overlap.
// Groups are disjoint (edges, stores) and LDS is read-only post-barrier;
// rotation changes NO FP summation order -> bit-identical output to R9.
// Everything else unchanged from R9:
//  - x/W1/W2 staged bf16+swizzled in LDS (coalesced); pi-permuted W2s.
//  - per-cb pipeline: phase1(cb) -> relu/repack (pi trick, in-lane) ->
//    phase-2 partial MFMAs; b1 folded into acc init; coalesced stores.
// Grid 512 = 8b x 64blk x 1024 edges, 512 thr, LDS 80KB, VGPR<=128 ->
// 2 blocks/CU, 16 waves/CU.

using frag_t  = __attribute__((ext_vector_type(8))) short;           // 8 bf16 = 4 VGPRs
using f32x4   = __attribute__((ext_vector_type(4))) float;
using f32x16  = __attribute__((ext_vector_type(16))) float;
using ushort8 = __attribute__((ext_vector_type(8))) unsigned short;

__device__ inline unsigned short f2bf(float f) {
    union { __hip_bfloat16 h; unsigned short u; } v;
    v.h = __float2bfloat16(f);          // RNE, hardware cvt on gfx950
    return v.u;
}

__device__ inline ushort8 pack8(f32x4 a, f32x4 b) {
    ushort8 o;
    o[0] = f2bf(a[0]); o[1] = f2bf(a[1]); o[2] = f2bf(a[2]); o[3] = f2bf(a[3]);
    o[4] = f2bf(b[0]); o[5] = f2bf(b[1]); o[6] = f2bf(b[2]); o[7] = f2bf(b[3]);
    return o;
}

__device__ inline frag_t packfrag(f32x4 a, f32x4 b) {
    union { ushort8 u; frag_t f; } v; v.u = pack8(a, b); return v.f;
}

// grid 512 = 8 batches x 64 blocks x 1024 edges; 8 waves/block, wave owns
// 128 edges (4 groups of 32, processed in wave-rotated order).
__global__ __launch_bounds__(512, 4)
void nri_mlp_fused(const float* __restrict__ x,
                   const float* __restrict__ W1,
                   const float* __restrict__ b1,
                   const float* __restrict__ W2,
                   const float* __restrict__ b2,
                   float* __restrict__ out) {
    extern __shared__ unsigned short smem[];
    unsigned short* W1s = smem;                        // 128x128 bf16 = 32 KB
    unsigned short* W2s = smem + 128 * 128;            //  64x128 bf16 = 16 KB (pi-permuted)
    unsigned short* Xs  = smem + 128 * 128 + 64 * 128; // 256x 64 bf16 = 32 KB

    const int tid  = threadIdx.x;
    const int wave = tid >> 6;                   // 0..7
    const int lane = tid & 63;
    const int hi   = lane >> 5;                  // half-wave index
    const int l5   = lane & 31;

    const int bx = blockIdx.x;
    const int b  = bx >> 6;                      // batch
    const int eb = (bx & 63) * 1024;             // block's first edge
    const int e0 = eb + wave * 128;              // this wave's first edge

    const float* xb = x + b * (256 * 64);

    // ---- cooperative staging (all coalesced global reads) ----
    // W1: data k-chunk c of row r at slot c^(r&7). 2048 chunks / 512 thr.
    #pragma unroll
    for (int i = 0; i < 4; ++i) {
        int cid = tid + i * 512;
        int row = cid >> 4, c = cid & 15;
        const float* s = W1 + row * 128 + c * 8;
        *(ushort8*)&W1s[row * 128 + (c ^ (row & 7)) * 8] =
            pack8(*(const f32x4*)s, *(const f32x4*)(s + 4));
    }
    // W2 at PERMUTED positions: position-chunk c holds hids base+{0..3,8..11},
    // base = 32(c>>2) + 16((c>>1)&1) + 4(c&1). 1024 chunks / 512 thr.
    #pragma unroll
    for (int i = 0; i < 2; ++i) {
        int cid = tid + i * 512;
        int row = cid >> 4, c = cid & 15;
        int base = 32 * (c >> 2) + 16 * ((c >> 1) & 1) + 4 * (c & 1);
        const float* s = W2 + row * 128 + base;
        *(ushort8*)&W2s[row * 128 + (c ^ (row & 7)) * 8] =
            pack8(*(const f32x4*)s, *(const f32x4*)(s + 8));
    }
    // X: node rows of 8 chunks, chunk c at slot c^(node&7). 2048 chunks / 512 thr.
    #pragma unroll
    for (int i = 0; i < 4; ++i) {
        int cid = tid + i * 512;
        int node = cid >> 3, c = cid & 7;
        const float* s = xb + node * 64 + c * 8;
        *(ushort8*)&Xs[node * 64 + (c ^ (node & 7)) * 8] =
            pack8(*(const f32x4*)s, *(const f32x4*)(s + 4));
    }
    __syncthreads();

    float b2v[2] = { b2[l5], b2[32 + l5] };      // flipped layout: 2 resident floats

    #pragma unroll 1   // contain register pressure: no cross-group hoisting
    for (int gi = 0; gi < 4; ++gi) {
        // wave-rotated group order: staggers LDS-phase vs store-phase across
        // the block's 8 waves. Groups are independent; output bit-identical.
        int g     = (gi + wave) & 3;
        int ebase = e0 + g * 32;
        if (ebase < 65280) {                     // partial-block guard (wave-uniform)

        // this lane's edge for gather / phase-1 (col = l5)
        int e    = ebase + l5;
        int recv = e / 255;
        int kk   = e - recv * 255;
        int send = kk + (kk >= recv ? 1 : 0);

        // ---- B-operand from LDS: af[ks] = edge feats k = 16ks + 8hi + (0..7) ----
        frag_t af[8];
        #pragma unroll
        for (int ks = 0; ks < 8; ++ks) {
            int node = (ks < 4) ? send : recv;           // k<64 <=> sender
            int c    = (ks & 3) * 2 + hi;
            af[ks] = *(const frag_t*)&Xs[node * 64 + (c ^ (node & 7)) * 8];
        }

        const float* b1p = b1;
        asm volatile("" : "+s"(b1p));    // opaque per group: no LICM residency

        f32x16 acc2[2];
        #pragma unroll
        for (int c2 = 0; c2 < 2; ++c2)
            #pragma unroll
            for (int r = 0; r < 16; ++r) acc2[c2][r] = 0.f;

        // ---- per-cb pipeline: phase1(cb) -> relu/repack -> phase2 partial ----
        #pragma unroll
        for (int cb = 0; cb < 4; ++cb) {
            // bias-init: acc reg 4m+q holds hid 32cb + 8m + 4hi + q
            f32x16 acc;
            #pragma unroll
            for (int m = 0; m < 4; ++m) {
                f32x4 bv = *(const f32x4*)(b1p + 32 * cb + 8 * m + 4 * hi);
                acc[4 * m + 0] = bv[0]; acc[4 * m + 1] = bv[1];
                acc[4 * m + 2] = bv[2]; acc[4 * m + 3] = bv[3];
            }
            // phase 1: Ht rows 32cb..+32 = W1 @ E^T (W1 streamed from LDS)
            #pragma unroll
            for (int ks = 0; ks < 8; ++ks) {
                int chunk = 2 * ks + hi;
                int row   = 32 * cb + l5;
                frag_t w1 = *(const frag_t*)&W1s[row * 128 + (chunk ^ (row & 7)) * 8];
                acc = __builtin_amdgcn_mfma_f32_32x32x16_bf16(w1, af[ks], acc, 0, 0, 0);
            }
            // relu + in-lane repack (pi trick): hf[2cb+s] = packed regs [8s..8s+8)
            f32x4 t[4];
            #pragma unroll
            for (int m = 0; m < 4; ++m)
                #pragma unroll
                for (int q = 0; q < 4; ++q) {
                    float v = acc[4 * m + q];
                    t[m][q] = v > 0.f ? v : 0.f;
                }
            frag_t hf0 = packfrag(t[0], t[1]);
            frag_t hf1 = packfrag(t[2], t[3]);
            // phase 2 partial: k-blocks ks2 = 2cb (hf0), 2cb+1 (hf1)
            #pragma unroll
            for (int s = 0; s < 2; ++s) {
                frag_t hf  = s ? hf1 : hf0;
                int chunk  = 2 * (2 * cb + s) + hi;
                #pragma unroll
                for (int c2 = 0; c2 < 2; ++c2) {
                    int row = 32 * c2 + l5;
                    frag_t w2 = *(const frag_t*)&W2s[row * 128 + (chunk ^ (row & 7)) * 8];
                    acc2[c2] = __builtin_amdgcn_mfma_f32_32x32x16_bf16(hf, w2, acc2[c2], 0, 0, 0);
                }
            }
        }

        // ---- store: col = l5 = out-feat (+32c2), reg r -> edge (r&3)+8(r>>2)+4hi.
        // Per instruction: two 128B-contiguous runs (full-line, coalesced).
        float* ob = out + ((long)b * 65280 + ebase) * 64;
        #pragma unroll
        for (int c2 = 0; c2 < 2; ++c2) {
            #pragma unroll
            for (int r = 0; r < 16; ++r) {
                int eo = (r & 3) + 8 * (r >> 2) + 4 * hi;
                ob[eo * 64 + 32 * c2 + l5] = acc2[c2][r] + b2v[c2];
            }
        }

        }   // partial-block guard
    }
}

extern "C" void kernel_launch(void* const* d_in, const int* in_sizes, int n_in,
                              void* d_out, int out_size, void* d_ws, size_t ws_size,
                              hipStream_t stream) {
    const float* x  = (const float*)d_in[0];
    // d_in[1] = rel_rec, d_in[2] = rel_send: one-hot incidence, replaced by index math
    const float* W1 = (const float*)d_in[3];
    const float* b1 = (const float*)d_in[4];
    const float* W2 = (const float*)d_in[5];
    const float* b2 = (const float*)d_in[6];
    (void)d_ws; (void)ws_size; (void)in_sizes; (void)n_in; (void)out_size;
    float* out = (float*)d_out;

    static bool attr_set = false;
    if (!attr_set) {
        hipFuncSetAttribute(reinterpret_cast<const void*>(nri_mlp_fused),
                            hipFuncAttributeMaxDynamicSharedMemorySize, 81920);
        attr_set = true;
    }
    nri_mlp_fused<<<512, 512, 81920, stream>>>(x, W1, b1, W2, b2, out);
}